// Round 5
// baseline (384.772 us; speedup 1.0000x reference)
//
#include <hip/hip_runtime.h>
#include <math.h>
#include <stdint.h>

// Problem constants (B=2, T=2048, D=1024, H=16, DH=64)
#define TSEQ   2048
#define DMODEL 1024
#define NHEAD  16
#define DHEAD  64
#define MROWS  4096   // B*T

typedef short bf16x8 __attribute__((ext_vector_type(8)));
typedef float f32x4  __attribute__((ext_vector_type(4)));
typedef uint64_t u64x2 __attribute__((ext_vector_type(2)));
typedef unsigned short u16;

typedef __attribute__((address_space(3))) unsigned int lds_u32_t;
typedef __attribute__((address_space(1))) unsigned int glb_u32_t;

static __device__ __forceinline__ u16 f2bf(float f) {
    unsigned u = __float_as_uint(f);
    u += 0x7FFFu + ((u >> 16) & 1u);   // round-to-nearest-even
    return (u16)(u >> 16);
}
static __device__ __forceinline__ float bf2f(u16 h) {
    return __uint_as_float(((unsigned)h) << 16);
}

// ---------------------------------------------------------------------------
// Transpose + cast: W[K][N] fp32  ->  Wt[N][K] bf16-bits
// ---------------------------------------------------------------------------
__global__ __launch_bounds__(256) void tc_kernel(
    const float* __restrict__ W, u16* __restrict__ Wt, int K, int N)
{
    __shared__ u16 tile[32][33];
    const int n0 = blockIdx.x * 32, k0 = blockIdx.y * 32;
    const int t = threadIdx.x;
    const int tx = t & 31, ty = t >> 5;           // 32 x 8
#pragma unroll
    for (int i = 0; i < 4; ++i) {
        int kk = ty + i * 8;
        tile[kk][tx] = f2bf(W[(size_t)(k0 + kk) * N + n0 + tx]);
    }
    __syncthreads();
#pragma unroll
    for (int i = 0; i < 4; ++i) {
        int nn = ty + i * 8;
        Wt[(size_t)(n0 + nn) * K + k0 + tx] = tile[tx][nn];
    }
}

// ---------------------------------------------------------------------------
// Pack 3 bias vectors (1024 each) into one 3072 fp32 vector
// ---------------------------------------------------------------------------
__global__ __launch_bounds__(256) void biaspack_kernel(
    const float* __restrict__ bq, const float* __restrict__ bk,
    const float* __restrict__ bv, float* __restrict__ o)
{
    const int i = blockIdx.x * 256 + threadIdx.x;
    if (i < 1024) o[i] = bq[i];
    else if (i < 2048) o[i] = bk[i - 1024];
    else if (i < 3072) o[i] = bv[i - 2048];
}

// ---------------------------------------------------------------------------
// bf16 transpose of V section: qkv[b*T + t][2048 + hd] -> vT[(b*16+h)*64+d][t]
// ---------------------------------------------------------------------------
__global__ __launch_bounds__(256) void vt_kernel(
    const u16* __restrict__ qkv, u16* __restrict__ vT)
{
    __shared__ __align__(16) u16 tile[64][72];
    const int bb = blockIdx.z;
    const int t0 = blockIdx.x * 64;
    const int c0 = blockIdx.y * 64;     // hd
    const int tid = threadIdx.x;
    const int r = tid >> 2;             // 0..63
    const int c = (tid & 3) * 16;       // 0,16,32,48
    const u16* src = qkv + (size_t)(bb * TSEQ + t0 + r) * 3072 + 2048 + c0 + c;
    *(bf16x8*)&tile[r][c]     = *(const bf16x8*)(src);
    *(bf16x8*)&tile[r][c + 8] = *(const bf16x8*)(src + 8);
    __syncthreads();
    u16 o[16];
#pragma unroll
    for (int j = 0; j < 16; ++j) o[j] = tile[c + j][r];
    u16* dst = vT + (size_t)(bb * 1024 + c0 + r) * TSEQ + t0 + c;
    *(bf16x8*)dst       = *(bf16x8*)&o[0];
    *(bf16x8*)(dst + 8) = *(bf16x8*)&o[8];
}

// ---------------------------------------------------------------------------
// LayerNorm(fp32 row of 1024) -> bf16 row. One block (256 thr) per row.
// ---------------------------------------------------------------------------
__global__ __launch_bounds__(256) void ln_kernel(
    const float* __restrict__ x, const float* __restrict__ g,
    const float* __restrict__ b, u16* __restrict__ out)
{
    const int row = blockIdx.x;
    const int t = threadIdx.x;
    const float4 v = ((const float4*)(x + (size_t)row * DMODEL))[t];
    float s  = v.x + v.y + v.z + v.w;
    float s2 = v.x * v.x + v.y * v.y + v.z * v.z + v.w * v.w;
#pragma unroll
    for (int m = 32; m >= 1; m >>= 1) { s += __shfl_xor(s, m); s2 += __shfl_xor(s2, m); }
    __shared__ float ps[4], ps2[4];
    if ((t & 63) == 0) { ps[t >> 6] = s; ps2[t >> 6] = s2; }
    __syncthreads();
    const float S  = ps[0] + ps[1] + ps[2] + ps[3];
    const float S2 = ps2[0] + ps2[1] + ps2[2] + ps2[3];
    const float mean = S * (1.0f / DMODEL);
    const float var  = S2 * (1.0f / DMODEL) - mean * mean;
    const float rstd = rsqrtf(var + 1e-5f);
    const float4 gg = ((const float4*)g)[t];
    const float4 bb = ((const float4*)b)[t];
    u16 o[4];
    o[0] = f2bf((v.x - mean) * rstd * gg.x + bb.x);
    o[1] = f2bf((v.y - mean) * rstd * gg.y + bb.y);
    o[2] = f2bf((v.z - mean) * rstd * gg.z + bb.z);
    o[3] = f2bf((v.w - mean) * rstd * gg.w + bb.w);
    *(short4*)(out + (size_t)row * DMODEL + t * 4) = *(short4*)o;
}

// ---------------------------------------------------------------------------
// gemm8: 256x256 tile, BK=32, 512 threads (8 waves, 2M x 4N), 4-slot LDS
// ring (128 KB), counted vmcnt(4) + 1 barrier per K-tile, T2 granule
// swizzle (g ^= (fr>>1)&3, both sides), T5 setprio around MFMA clusters.
//   EPI 0: +bias, store bf16 (LDS-coalesced)
//   EPI 1: +bias, exact GELU, store bf16 (LDS-coalesced)
// A2 (if non-null) used for output cols >= 1024 (fused QKV).
// ---------------------------------------------------------------------------
template <int EPI>
__global__ __launch_bounds__(512, 2) void gemm8(
    const u16* __restrict__ A, const u16* __restrict__ A2,
    const u16* __restrict__ Wt, const float* __restrict__ bias,
    u16* __restrict__ Cb, int N, int K, int gx, int cx)
{
    __shared__ __align__(16) char smem8[131072];   // 4 slots x (A 16KB + B 16KB)

    // 2-D XCD chunking over the 1-D tile grid (bijective; nwg % 8 == 0)
    const int bid = blockIdx.x;
    const int xcd = bid & 7, jj = bid >> 3;
    const int sx = gx / cx;
    const int sy = (gridDim.x >> 3) / sx;
    const int xr = xcd / cx, xc = xcd % cx;
    const int jr = jj / sx, jc = jj % sx;
    const int m0 = (xr * sy + jr) * 256;
    const int n0 = (xc * sx + jc) * 256;

    const int tid = threadIdx.x;
    const int lane = tid & 63;
    const int w = tid >> 6;                 // 0..7
    const int wr = w >> 2, wc = w & 3;      // 2M x 4N
    const int fr = lane & 15, fq = lane >> 4;
    const int swzoff = (fq ^ ((fr >> 1) & 3)) * 16;   // read-side granule swizzle

    const u16* Ause = (A2 != nullptr && n0 >= 1024) ? A2 : A;

    // pre-swizzled global stage sources: thread t stages 16B granule (t&3)
    // of row (t>>2); data must be global granule (t&3)^((t>>3)&3)
    const int strow = tid >> 2;                       // 0..127
    const int stcol = ((tid & 3) ^ ((tid >> 3) & 3)) * 8;
    const u16* gAs = Ause + (size_t)(m0 + strow) * K + stcol;
    const u16* gBs = Wt  + (size_t)(n0 + strow) * K + stcol;

#define STAGE_A(slot, kt) do {                                                           \
    const u16* _s = gAs + (size_t)(kt) * 32;                                             \
    char* _l = smem8 + (slot) * 32768 + w * 1024;                                        \
    __builtin_amdgcn_global_load_lds((const glb_u32_t*)_s, (lds_u32_t*)_l, 16, 0, 0);    \
    __builtin_amdgcn_global_load_lds((const glb_u32_t*)(_s + (size_t)128 * K),           \
                                     (lds_u32_t*)(_l + 8192), 16, 0, 0);                 \
} while (0)
#define STAGE_B(slot, kt) do {                                                           \
    const u16* _s = gBs + (size_t)(kt) * 32;                                             \
    char* _l = smem8 + (slot) * 32768 + 16384 + w * 1024;                                \
    __builtin_amdgcn_global_load_lds((const glb_u32_t*)_s, (lds_u32_t*)_l, 16, 0, 0);    \
    __builtin_amdgcn_global_load_lds((const glb_u32_t*)(_s + (size_t)128 * K),           \
                                     (lds_u32_t*)(_l + 8192), 16, 0, 0);                 \
} while (0)

    f32x4 zero = {0.f, 0.f, 0.f, 0.f};
    f32x4 acc[8][4];
#pragma unroll
    for (int mi = 0; mi < 8; ++mi)
#pragma unroll
        for (int ni = 0; ni < 4; ++ni) acc[mi][ni] = zero;

    const int nt = K >> 5;                  // K-tiles of 32
    // prologue: tiles 0 and 1 in flight (8 vmem instrs/thread)
    STAGE_A(0, 0); STAGE_B(0, 0);
    STAGE_A(1, 1); STAGE_B(1, 1);

    const int abase = (wr * 128 + fr) * 64 + swzoff;          // + mi*1024
    const int bbase = 16384 + (wc * 64 + fr) * 64 + swzoff;   // + ni*1024

    for (int t = 0; t < nt; ++t) {
        const int slot = t & 3;
        const char* sb = smem8 + slot * 32768;
        asm volatile("s_waitcnt vmcnt(4)" ::: "memory");
        __builtin_amdgcn_s_barrier();       // tile t fully staged, block-wide

        // phase 0: B frags + A frags (mi 0..3), stage A(t+2)
        bf16x8 bfr[4], af[4];
#pragma unroll
        for (int ni = 0; ni < 4; ++ni)
            bfr[ni] = *(const bf16x8*)(sb + bbase + ni * 1024);
#pragma unroll
        for (int mi = 0; mi < 4; ++mi)
            af[mi] = *(const bf16x8*)(sb + abase + mi * 1024);
        if (t + 2 < nt) STAGE_A((t + 2) & 3, t + 2);
        __builtin_amdgcn_s_setprio(1);
#pragma unroll
        for (int mi = 0; mi < 4; ++mi)
#pragma unroll
            for (int ni = 0; ni < 4; ++ni)
                acc[mi][ni] = __builtin_amdgcn_mfma_f32_16x16x32_bf16(af[mi], bfr[ni], acc[mi][ni], 0, 0, 0);
        __builtin_amdgcn_s_setprio(0);

        // phase 1: A frags (mi 4..7), stage B(t+2)
        bf16x8 af2[4];
#pragma unroll
        for (int mi = 0; mi < 4; ++mi)
            af2[mi] = *(const bf16x8*)(sb + abase + (mi + 4) * 1024);
        if (t + 2 < nt) STAGE_B((t + 2) & 3, t + 2);
        __builtin_amdgcn_s_setprio(1);
#pragma unroll
        for (int mi = 0; mi < 4; ++mi)
#pragma unroll
            for (int ni = 0; ni < 4; ++ni)
                acc[mi + 4][ni] = __builtin_amdgcn_mfma_f32_16x16x32_bf16(af2[mi], bfr[ni], acc[mi + 4][ni], 0, 0, 0);
        __builtin_amdgcn_s_setprio(0);
    }
#undef STAGE_A
#undef STAGE_B

    // epilogue: coalesced bf16 stores via LDS, two 128-row halves.
    // cs stride 260 u16 (520B) -> conflict-free scatter writes.
    u16* cs = (u16*)smem8;
#pragma unroll
    for (int hh = 0; hh < 2; ++hh) {
        __builtin_amdgcn_s_barrier();
        if (wr == hh) {
#pragma unroll
            for (int ni = 0; ni < 4; ++ni) {
                const int col = wc * 64 + ni * 16 + fr;
                const float bv = bias[n0 + col];
#pragma unroll
                for (int mi = 0; mi < 8; ++mi) {
#pragma unroll
                    for (int j = 0; j < 4; ++j) {
                        float val = acc[mi][ni][j] + bv;
                        if (EPI == 1)
                            val = 0.5f * val * (1.0f + erff(val * 0.70710678118654752f));
                        cs[(mi * 16 + fq * 4 + j) * 260 + col] = f2bf(val);
                    }
                }
            }
        }
        __builtin_amdgcn_s_barrier();
        const int cc = (tid & 31) * 8;
#pragma unroll
        for (int p = 0; p < 8; ++p) {
            const int row = p * 16 + (tid >> 5);
            const uint64_t lo = *(const uint64_t*)&cs[row * 260 + cc];
            const uint64_t hi = *(const uint64_t*)&cs[row * 260 + cc + 4];
            u64x2 v; v.x = lo; v.y = hi;
            *(u64x2*)&Cb[(size_t)(m0 + hh * 128 + row) * N + n0 + cc] = v;
        }
    }
}

// ---------------------------------------------------------------------------
// GEMM (128x128, 2-phase pipeline): C = A * Wt^T (+bias) (+epilogue)
//   EPI 2: +bias, += resid (fp32), store fp32
//   EPI 3: split-K partial, no bias, fp32 to (blockIdx.y ? Cf2 : Cf)
// ---------------------------------------------------------------------------
template <int EPI>
__global__ __launch_bounds__(256) void gemm_bt(
    const u16* __restrict__ A, const u16* __restrict__ A2,
    const u16* __restrict__ Wt,
    const float* __restrict__ bias, const float* __restrict__ resid,
    u16* __restrict__ Cb, float* __restrict__ Cf, float* __restrict__ Cf2,
    int N, int K, int kl, int gx, int cx)
{
    extern __shared__ __align__(16) char smem[];   // 2x16KB stage

    const int bid = blockIdx.x;
    const int xcd = bid & 7, jj = bid >> 3;
    const int sx = gx / cx;
    const int sy = (gridDim.x >> 3) / sx;
    const int xr = xcd / cx, xc = xcd % cx;
    const int jr = jj / sx, jc = jj % sx;
    const int m0 = (xr * sy + jr) * 128;
    const int n0 = (xc * sx + jc) * 128;
    const int kofs = blockIdx.y * kl;

    const int t = threadIdx.x;
    const int lane = t & 63;
    const int wv = t >> 6;
    const int wr = wv >> 1, wc = wv & 1;

    const u16* Ause = (A2 != nullptr && n0 >= 1024) ? A2 : A;

    const int strow = t >> 2;            // 0..63
    const int stcol = (t & 3) * 8;
    const u16* gA  = Ause + (size_t)(m0 + strow) * K + kofs + stcol;
    const u16* gA2 = gA + (size_t)64 * K;
    const u16* gB  = Wt + (size_t)(n0 + strow) * K + kofs + stcol;
    const u16* gB2 = gB + (size_t)64 * K;

#define STAGE(bufi, k0) do {                                                            \
    char* _b = smem + (bufi) * 16384 + wv * 1024;                                       \
    __builtin_amdgcn_global_load_lds((const glb_u32_t*)(gA  + (k0)), (lds_u32_t*)(_b),          16, 0, 0); \
    __builtin_amdgcn_global_load_lds((const glb_u32_t*)(gA2 + (k0)), (lds_u32_t*)(_b + 4096),  16, 0, 0); \
    __builtin_amdgcn_global_load_lds((const glb_u32_t*)(gB  + (k0)), (lds_u32_t*)(_b + 8192),  16, 0, 0); \
    __builtin_amdgcn_global_load_lds((const glb_u32_t*)(gB2 + (k0)), (lds_u32_t*)(_b + 12288), 16, 0, 0); \
} while (0)

    f32x4 zero = {0.f, 0.f, 0.f, 0.f};
    f32x4 acc[4][4];
#pragma unroll
    for (int mi = 0; mi < 4; ++mi)
#pragma unroll
        for (int ni = 0; ni < 4; ++ni) acc[mi][ni] = zero;

    const int fr = lane & 15, fq = lane >> 4;
    const int nk = kl >> 5;

    STAGE(0, 0);
    STAGE(1, 32);

    for (int kt = 0; kt < nk; ++kt) {
        const int cur = kt & 1;
        if (kt < nk - 1) { asm volatile("s_waitcnt vmcnt(4)" ::: "memory"); }
        else             { asm volatile("s_waitcnt vmcnt(0)" ::: "memory"); }
        __builtin_amdgcn_s_barrier();

        const u16* As_ = (const u16*)smem + cur * 8192;
        const u16* Bs_ = As_ + 4096;
        bf16x8 af[4], bfr[4];
#pragma unroll
        for (int mi = 0; mi < 4; ++mi)
            af[mi] = *(const bf16x8*)&As_[(wr * 64 + mi * 16 + fr) * 32 + fq * 8];
#pragma unroll
        for (int ni = 0; ni < 4; ++ni)
            bfr[ni] = *(const bf16x8*)&Bs_[(wc * 64 + ni * 16 + fr) * 32 + fq * 8];

        __builtin_amdgcn_s_setprio(1);
#pragma unroll
        for (int mi = 0; mi < 4; ++mi)
#pragma unroll
            for (int ni = 0; ni < 4; ++ni)
                acc[mi][ni] = __builtin_amdgcn_mfma_f32_16x16x32_bf16(af[mi], bfr[ni], acc[mi][ni], 0, 0, 0);
        __builtin_amdgcn_s_setprio(0);
        __builtin_amdgcn_sched_barrier(0);
        __builtin_amdgcn_s_barrier();
        if (kt + 2 < nk) STAGE(cur, (kt + 2) << 5);
    }
#undef STAGE

    float* Cpart = (EPI == 3) ? (blockIdx.y ? Cf2 : Cf) : Cf;
#pragma unroll
    for (int ni = 0; ni < 4; ++ni) {
        const int col = n0 + wc * 64 + ni * 16 + fr;
        const float bv = (EPI == 3) ? 0.f : bias[col];
#pragma unroll
        for (int mi = 0; mi < 4; ++mi) {
#pragma unroll
            for (int j = 0; j < 4; ++j) {
                const int row = m0 + wr * 64 + mi * 16 + fq * 4 + j;
                float val = acc[mi][ni][j] + bv;
                if (EPI == 2)
                    Cf[(size_t)row * N + col] = val + resid[(size_t)row * N + col];
                else
                    Cpart[(size_t)row * N + col] = val;
            }
        }
    }
}

// ---------------------------------------------------------------------------
// Split-K reduce: out = p0 + p1 + bias + resid  (fp32, vectorized)
// ---------------------------------------------------------------------------
__global__ __launch_bounds__(256) void redk_kernel(
    const float* __restrict__ p0, const float* __restrict__ p1,
    const float* __restrict__ bias, const float* __restrict__ resid,
    float* __restrict__ out, int n4, int ncols)
{
    const int stride = gridDim.x * 256;
    for (int i = blockIdx.x * 256 + threadIdx.x; i < n4; i += stride) {
        const float4 a = ((const float4*)p0)[i];
        const float4 b = ((const float4*)p1)[i];
        const float4 r = ((const float4*)resid)[i];
        const float4 bb = *(const float4*)&bias[(i * 4) & (ncols - 1)];
        float4 o;
        o.x = a.x + b.x + bb.x + r.x;
        o.y = a.y + b.y + bb.y + r.y;
        o.z = a.z + b.z + bb.z + r.z;
        o.w = a.w + b.w + bb.w + r.w;
        ((float4*)out)[i] = o;
    }
}

// ---------------------------------------------------------------------------
// Banded attention via MFMA. One wave = 16 queries x 80-key aligned window
// (supports band <= 32). q,k read from fused qkv [4096][3072]; ctx -> [4096][1024].
// ---------------------------------------------------------------------------
__global__ __launch_bounds__(256) void battn_kernel(
    const u16* __restrict__ qkv, const u16* __restrict__ vT,
    u16* __restrict__ ctx, const int* __restrict__ band_ptr)
{
    __shared__ __align__(16) u16 P[4][16][104];
    const int band = *band_ptr;
    const int bid = blockIdx.x;
    const int tile = bid & 31;
    const int h = (bid >> 5) & 15;
    const int b = bid >> 9;
    const int w = threadIdx.x >> 6;
    const int lane = threadIdx.x & 63;
    const int fr = lane & 15, fq = lane >> 4;
    const int t0 = tile * 64 + w * 16;

    const size_t qbase = ((size_t)b * TSEQ) * 3072 + h * DHEAD;          // q cols
    const size_t kbase = qbase + 1024;                                   // k cols
    const size_t cbase = ((size_t)b * TSEQ) * DMODEL + h * DHEAD;        // ctx

    const bf16x8 aq0 = *(const bf16x8*)&qkv[qbase + (size_t)(t0 + fr) * 3072 + fq * 8];
    const bf16x8 aq1 = *(const bf16x8*)&qkv[qbase + (size_t)(t0 + fr) * 3072 + 32 + fq * 8];

    const int kb0 = t0 - 32;
    const f32x4 zero = {0.f, 0.f, 0.f, 0.f};

    f32x4 sc[5];
#pragma unroll
    for (int kt = 0; kt < 5; ++kt) {
        const int srow = kb0 + kt * 16 + fr;
        const int scl = min(max(srow, 0), TSEQ - 1);
        const bf16x8 kf0 = *(const bf16x8*)&qkv[kbase + (size_t)scl * 3072 + fq * 8];
        const bf16x8 kf1 = *(const bf16x8*)&qkv[kbase + (size_t)scl * 3072 + 32 + fq * 8];
        f32x4 a = zero;
        a = __builtin_amdgcn_mfma_f32_16x16x32_bf16(aq0, kf0, a, 0, 0, 0);
        a = __builtin_amdgcn_mfma_f32_16x16x32_bf16(aq1, kf1, a, 0, 0, 0);
        sc[kt] = a;
    }

    float mx[4], l[4];
#pragma unroll
    for (int j = 0; j < 4; ++j) mx[j] = -1e30f;
#pragma unroll
    for (int kt = 0; kt < 5; ++kt) {
        const int s = kb0 + kt * 16 + fr;
#pragma unroll
        for (int j = 0; j < 4; ++j) {
            const int tq = t0 + fq * 4 + j;
            const bool ok = (s >= 0) && (s < TSEQ) && (abs(tq - s) <= band);
            const float vv = ok ? sc[kt][j] * 0.125f : -1e30f;
            sc[kt][j] = vv;
            mx[j] = fmaxf(mx[j], vv);
        }
    }
#pragma unroll
    for (int m = 1; m <= 8; m <<= 1)
#pragma unroll
        for (int j = 0; j < 4; ++j) mx[j] = fmaxf(mx[j], __shfl_xor(mx[j], m));

#pragma unroll
    for (int j = 0; j < 4; ++j) l[j] = 0.f;
#pragma unroll
    for (int kt = 0; kt < 5; ++kt)
#pragma unroll
        for (int j = 0; j < 4; ++j) {
            const float p = __expf(sc[kt][j] - mx[j]);
            sc[kt][j] = p;
            l[j] += p;
        }
#pragma unroll
    for (int m = 1; m <= 8; m <<= 1)
#pragma unroll
        for (int j = 0; j < 4; ++j) l[j] += __shfl_xor(l[j], m);

#pragma unroll
    for (int kt = 0; kt < 5; ++kt)
#pragma unroll
        for (int j = 0; j < 4; ++j)
            P[w][fq * 4 + j][kt * 16 + fr] = f2bf(sc[kt][j]);
    {
        const short4 z4 = {0, 0, 0, 0};
        *(short4*)&P[w][fr][80 + fq * 4] = z4;
    }
    __syncthreads();

    bf16x8 pa[3];
#pragma unroll
    for (int c = 0; c < 3; ++c)
        pa[c] = *(const bf16x8*)&P[w][fr][c * 32 + fq * 8];

    const size_t vbase = ((size_t)(b * NHEAD + h) * DHEAD) * TSEQ;
    f32x4 cacc[4];
#pragma unroll
    for (int dt = 0; dt < 4; ++dt) cacc[dt] = zero;
#pragma unroll
    for (int dt = 0; dt < 4; ++dt) {
#pragma unroll
        for (int c = 0; c < 3; ++c) {
            const int s8 = kb0 + c * 32 + fq * 8;
            const int s8c = min(max(s8, 0), TSEQ - 8);
            const bf16x8 vf = *(const bf16x8*)&vT[vbase + (size_t)(dt * 16 + fr) * TSEQ + s8c];
            cacc[dt] = __builtin_amdgcn_mfma_f32_16x16x32_bf16(pa[c], vf, cacc[dt], 0, 0, 0);
        }
    }

    float rl[4];
#pragma unroll
    for (int j = 0; j < 4; ++j) rl[j] = 1.0f / l[j];
#pragma unroll
    for (int dt = 0; dt < 4; ++dt)
#pragma unroll
        for (int j = 0; j < 4; ++j)
            ctx[cbase + (size_t)(t0 + fq * 4 + j) * DMODEL + dt * 16 + fr] =
                f2bf(cacc[dt][j] * rl[j]);
}

// ---------------------------------------------------------------------------
extern "C" void kernel_launch(void* const* d_in, const int* in_sizes, int n_in,
                              void* d_out, int out_size, void* d_ws, size_t ws_size,
                              hipStream_t stream) {
    const float* x_ref  = (const float*)d_in[0];
    const float* x_mem  = (const float*)d_in[1];
    const float* ln_q_g = (const float*)d_in[2];
    const float* ln_q_b = (const float*)d_in[3];
    const float* ln_kv_g= (const float*)d_in[4];
    const float* ln_kv_b= (const float*)d_in[5];
    const float* Wq = (const float*)d_in[6];
    const float* bq = (const float*)d_in[7];
    const float* Wk = (const float*)d_in[8];
    const float* bk = (const float*)d_in[9];
    const float* Wv = (const float*)d_in[10];
    const float* bv = (const float*)d_in[11];
    const float* Wo = (const float*)d_in[12];
    const float* bo = (const float*)d_in[13];
    const float* ln_f_g = (const float*)d_in[14];
    const float* ln_f_b = (const float*)d_in[15];
    const float* W1 = (const float*)d_in[16];
    const float* b1 = (const float*)d_in[17];
    const float* W2 = (const float*)d_in[18];
    const float* b2 = (const float*)d_in[19];
    const int*  band = (const int*)d_in[20];
    float* out = (float*)d_out;

    char* ws = (char*)d_ws;
    const size_t MB = 1024 * 1024;
    if (ws_size < 128 * MB) return;
    u16*   wt_qkv = (u16*)(ws + 0 * MB);
    u16*   wt_o   = (u16*)(ws + 6 * MB);
    u16*   wt_1   = (u16*)(ws + 8 * MB);
    u16*   wt_2   = (u16*)(ws + 16 * MB);
    float* bqkv   = (float*)(ws + 24 * MB);
    u16*   aq     = (u16*)(ws + 25 * MB);
    u16*   akv    = (u16*)(ws + 33 * MB);
    u16*   qkvb   = (u16*)(ws + 41 * MB);
    u16*   vTb    = (u16*)(ws + 65 * MB);
    u16*   ctxb   = (u16*)(ws + 73 * MB);
    float* y      = (float*)(ws + 81 * MB);
    u16*   hb     = (u16*)(ws + 97 * MB);
    u16*   a1     = (u16*)(ws + 25 * MB);
    float* p0     = (float*)(ws + 57 * MB);
    float* p1     = (float*)(ws + 97 * MB);

    dim3 blk(256);
    const size_t SM_GEMM = 32768;   // 2x16KB stage buffers

    tc_kernel<<<dim3(32, 32),  blk, 0, stream>>>(Wq, wt_qkv,               1024, 1024);
    tc_kernel<<<dim3(32, 32),  blk, 0, stream>>>(Wk, wt_qkv + 1024 * 1024, 1024, 1024);
    tc_kernel<<<dim3(32, 32),  blk, 0, stream>>>(Wv, wt_qkv + 2048 * 1024, 1024, 1024);
    tc_kernel<<<dim3(32, 32),  blk, 0, stream>>>(Wo, wt_o, 1024, 1024);
    tc_kernel<<<dim3(128, 32), blk, 0, stream>>>(W1, wt_1, 1024, 4096);
    tc_kernel<<<dim3(32, 128), blk, 0, stream>>>(W2, wt_2, 4096, 1024);
    biaspack_kernel<<<12, blk, 0, stream>>>(bq, bk, bv, bqkv);
    ln_kernel<<<MROWS, blk, 0, stream>>>(x_ref, ln_q_g, ln_q_b, aq);
    ln_kernel<<<MROWS, blk, 0, stream>>>(x_mem, ln_kv_g, ln_kv_b, akv);
    // fused QKV projection: [4096][3072]; 256^2 tiles 16y x 12x; XCD 2x6 chunks
    gemm8<0><<<dim3(192), dim3(512), 0, stream>>>(aq, akv, wt_qkv, bqkv, qkvb,
                                                  3072, 1024, 12, 2);
    vt_kernel<<<dim3(32, 16, 2), blk, 0, stream>>>(qkvb, vTb);
    battn_kernel<<<1024, blk, 0, stream>>>(qkvb, vTb, ctxb, band);
    // y = x_refined + ctx @ Wo + bo; 128^2 tiles 32y x 8x
    gemm_bt<2><<<dim3(256), blk, SM_GEMM, stream>>>(ctxb, nullptr, wt_o, bo, x_ref,
                                                    nullptr, y, nullptr,
                                                    1024, 1024, 1024, 8, 1);
    ln_kernel<<<MROWS, blk, 0, stream>>>(y, ln_f_g, ln_f_b, hb);
    // FFN1: GELU(hb @ W1 + b1); 256^2 tiles 16y x 16x; XCD 2x8 chunks
    gemm8<1><<<dim3(256), dim3(512), 0, stream>>>(hb, nullptr, wt_1, b1, a1,
                                                  4096, 1024, 16, 2);
    // FFN2 split-K=2; 128^2 tiles 32y x 8x
    gemm_bt<3><<<dim3(256, 2), blk, SM_GEMM, stream>>>(a1, nullptr, wt_2, nullptr, nullptr,
                                                       nullptr, p0, p1,
                                                       1024, 4096, 2048, 8, 1);
    redk_kernel<<<2048, blk, 0, stream>>>(p0, p1, b2, y, out, MROWS * 1024 / 4, 1024);
}

// Round 6
// 382.779 us; speedup vs baseline: 1.0052x; 1.0052x over previous
//
#include <hip/hip_runtime.h>
#include <math.h>
#include <stdint.h>

// Problem constants (B=2, T=2048, D=1024, H=16, DH=64)
#define TSEQ   2048
#define DMODEL 1024
#define NHEAD  16
#define DHEAD  64
#define MROWS  4096   // B*T

typedef short bf16x8 __attribute__((ext_vector_type(8)));
typedef float f32x4  __attribute__((ext_vector_type(4)));
typedef uint64_t u64x2 __attribute__((ext_vector_type(2)));
typedef unsigned short u16;

typedef __attribute__((address_space(3))) unsigned int lds_u32_t;
typedef __attribute__((address_space(1))) unsigned int glb_u32_t;

static __device__ __forceinline__ u16 f2bf(float f) {
    unsigned u = __float_as_uint(f);
    u += 0x7FFFu + ((u >> 16) & 1u);   // round-to-nearest-even
    return (u16)(u >> 16);
}
static __device__ __forceinline__ float bf2f(u16 h) {
    return __uint_as_float(((unsigned)h) << 16);
}

// ---------------------------------------------------------------------------
// Transpose + cast: W[K][N] fp32  ->  Wt[N][K] bf16-bits
// ---------------------------------------------------------------------------
__global__ __launch_bounds__(256) void tc_kernel(
    const float* __restrict__ W, u16* __restrict__ Wt, int K, int N)
{
    __shared__ u16 tile[32][33];
    const int n0 = blockIdx.x * 32, k0 = blockIdx.y * 32;
    const int t = threadIdx.x;
    const int tx = t & 31, ty = t >> 5;           // 32 x 8
#pragma unroll
    for (int i = 0; i < 4; ++i) {
        int kk = ty + i * 8;
        tile[kk][tx] = f2bf(W[(size_t)(k0 + kk) * N + n0 + tx]);
    }
    __syncthreads();
#pragma unroll
    for (int i = 0; i < 4; ++i) {
        int nn = ty + i * 8;
        Wt[(size_t)(n0 + nn) * K + k0 + tx] = tile[tx][nn];
    }
}

// ---------------------------------------------------------------------------
// Pack 3 bias vectors (1024 each) into one 3072 fp32 vector
// ---------------------------------------------------------------------------
__global__ __launch_bounds__(256) void biaspack_kernel(
    const float* __restrict__ bq, const float* __restrict__ bk,
    const float* __restrict__ bv, float* __restrict__ o)
{
    const int i = blockIdx.x * 256 + threadIdx.x;
    if (i < 1024) o[i] = bq[i];
    else if (i < 2048) o[i] = bk[i - 1024];
    else if (i < 3072) o[i] = bv[i - 2048];
}

// ---------------------------------------------------------------------------
// bf16 transpose of V section: qkv[b*T + t][2048 + hd] -> vT[(b*16+h)*64+d][t]
// ---------------------------------------------------------------------------
__global__ __launch_bounds__(256) void vt_kernel(
    const u16* __restrict__ qkv, u16* __restrict__ vT)
{
    __shared__ __align__(16) u16 tile[64][72];
    const int bb = blockIdx.z;
    const int t0 = blockIdx.x * 64;
    const int c0 = blockIdx.y * 64;     // hd
    const int tid = threadIdx.x;
    const int r = tid >> 2;             // 0..63
    const int c = (tid & 3) * 16;       // 0,16,32,48
    const u16* src = qkv + (size_t)(bb * TSEQ + t0 + r) * 3072 + 2048 + c0 + c;
    *(bf16x8*)&tile[r][c]     = *(const bf16x8*)(src);
    *(bf16x8*)&tile[r][c + 8] = *(const bf16x8*)(src + 8);
    __syncthreads();
    u16 o[16];
#pragma unroll
    for (int j = 0; j < 16; ++j) o[j] = tile[c + j][r];
    u16* dst = vT + (size_t)(bb * 1024 + c0 + r) * TSEQ + t0 + c;
    *(bf16x8*)dst       = *(bf16x8*)&o[0];
    *(bf16x8*)(dst + 8) = *(bf16x8*)&o[8];
}

// ---------------------------------------------------------------------------
// LayerNorm(fp32 row of 1024) -> bf16 row. One block (256 thr) per row.
// ---------------------------------------------------------------------------
__global__ __launch_bounds__(256) void ln_kernel(
    const float* __restrict__ x, const float* __restrict__ g,
    const float* __restrict__ b, u16* __restrict__ out)
{
    const int row = blockIdx.x;
    const int t = threadIdx.x;
    const float4 v = ((const float4*)(x + (size_t)row * DMODEL))[t];
    float s  = v.x + v.y + v.z + v.w;
    float s2 = v.x * v.x + v.y * v.y + v.z * v.z + v.w * v.w;
#pragma unroll
    for (int m = 32; m >= 1; m >>= 1) { s += __shfl_xor(s, m); s2 += __shfl_xor(s2, m); }
    __shared__ float ps[4], ps2[4];
    if ((t & 63) == 0) { ps[t >> 6] = s; ps2[t >> 6] = s2; }
    __syncthreads();
    const float S  = ps[0] + ps[1] + ps[2] + ps[3];
    const float S2 = ps2[0] + ps2[1] + ps2[2] + ps2[3];
    const float mean = S * (1.0f / DMODEL);
    const float var  = S2 * (1.0f / DMODEL) - mean * mean;
    const float rstd = rsqrtf(var + 1e-5f);
    const float4 gg = ((const float4*)g)[t];
    const float4 bb = ((const float4*)b)[t];
    u16 o[4];
    o[0] = f2bf((v.x - mean) * rstd * gg.x + bb.x);
    o[1] = f2bf((v.y - mean) * rstd * gg.y + bb.y);
    o[2] = f2bf((v.z - mean) * rstd * gg.z + bb.z);
    o[3] = f2bf((v.w - mean) * rstd * gg.w + bb.w);
    *(short4*)(out + (size_t)row * DMODEL + t * 4) = *(short4*)o;
}

// ---------------------------------------------------------------------------
// gemm256: m201-style 256x256 8-phase kernel. BK=64, 2 K-tiles/iter,
// 512 threads (8 waves, 2M x 4N), LDS = 2 buf x {A,B} x 2 halves x 128x64
// = 128 KB. Counted vmcnt(6) at phases 4/8 only (3 half-tiles in flight).
// XOR bank swizzle: LDS slot S = granule ^ (row&7), applied as inverse on
// the global stage source (linear gload_lds dest) and on ds_read addrs.
//   EPI 0: +bias, store bf16       EPI 1: +bias, exact GELU, store bf16
// A2 (if non-null) used for output cols >= 1024 (fused QKV).
// ---------------------------------------------------------------------------
#define MFMA16 __builtin_amdgcn_mfma_f32_16x16x32_bf16

template <int EPI>
__global__ __launch_bounds__(512, 2) void gemm256(
    const u16* __restrict__ A, const u16* __restrict__ A2,
    const u16* __restrict__ Wt, const float* __restrict__ bias,
    u16* __restrict__ Cb, int N, int K, int gx, int cx)
{
    __shared__ __align__(16) char smem8[131072];
    // layout: buf c (0,1) @ c*65536; within: Ah0 @0, Ah1 @16384,
    //         Bh0 @32768, Bh1 @49152. Each half: 128 rows x 128 B.

    // 2-D XCD chunking (bijective; gridDim.x % 8 == 0)
    const int bid = blockIdx.x;
    const int xcd = bid & 7, jj = bid >> 3;
    const int sx = gx / cx;
    const int sy = (gridDim.x >> 3) / sx;
    const int xr = xcd / cx, xc = xcd % cx;
    const int jr = jj / sx, jc = jj % sx;
    const int m0 = (xr * sy + jr) * 256;
    const int n0 = (xc * sx + jc) * 256;

    const int tid = threadIdx.x;
    const int lane = tid & 63;
    const int w = tid >> 6;                 // 0..7
    const int wr = w >> 2, wc = w & 3;      // 2M x 4N
    const int fr = lane & 15, fq = lane >> 4;
    const int s0 = (fq ^ (fr & 7)) * 16;    // swizzled slot byte offset (kk=0)

    const u16* Ause = (A2 != nullptr && n0 >= 1024) ? A2 : A;

    // stage source: thread covers row tid>>3 (+64 for 2nd load), granule
    // (tid&7)^((tid>>3)&7)  -> lands linearly at LDS (row, slot=tid&7)
    const int strow = tid >> 3;
    const int stcol = ((tid & 7) ^ ((tid >> 3) & 7)) * 8;
    const u16* gA0 = Ause + (size_t)(m0 + strow) * K + stcol;
    const u16* gA1 = gA0 + (size_t)128 * K;
    const u16* gB0 = Wt + (size_t)(n0 + strow) * K + stcol;
    const u16* gB1 = gB0 + (size_t)128 * K;
    const size_t jstep = (size_t)64 * K;

#define SH(ldsoff, gp, kt) do {                                                          \
    char* _l = smem8 + (ldsoff) + w * 1024;                                              \
    const u16* _g = (gp) + (size_t)(kt) * 64;                                            \
    __builtin_amdgcn_global_load_lds((const glb_u32_t*)_g, (lds_u32_t*)_l, 16, 0, 0);    \
    __builtin_amdgcn_global_load_lds((const glb_u32_t*)(_g + jstep),                     \
                                     (lds_u32_t*)(_l + 8192), 16, 0, 0);                 \
} while (0)

    f32x4 acc[8][4];
#pragma unroll
    for (int m = 0; m < 8; ++m)
#pragma unroll
        for (int n = 0; n < 4; ++n) acc[m][n] = (f32x4){0.f, 0.f, 0.f, 0.f};

    // reader base offsets (byte). kk=1 applies ^64 (slot bit2 flip).
    const int aob = wr * 16384 + fr * 128 + s0;                              // + mh*8192 + mi*2048
    const int bob = 32768 + (wc >> 1) * 16384 + ((wc & 1) * 64 + fr) * 128 + s0;  // + ni*2048

    const int nt = K >> 6;          // K-tiles of 64
    const int niter = nt >> 1;

    // prologue: buf0 (ktile0) 4 halves + buf1.Ah0 (ktile1); wait buf0.
    SH(0,     gA0, 0); SH(16384, gA1, 0); SH(32768, gB0, 0); SH(49152, gB1, 0);
    SH(65536, gA0, 1);
    asm volatile("s_waitcnt vmcnt(6)" ::: "memory");
    __builtin_amdgcn_s_barrier();

    bf16x8 af[4][2], bfr[4][2];

    for (int i = 0; i < niter; ++i) {
        const bool more = (i + 1 < niter);
        const int kt1 = 2 * i + 1, kt2 = kt1 + 1, kt3 = kt1 + 2;
        const char* sb0 = smem8;
        const char* sb1 = smem8 + 65536;

        // ---------------- buf0 = ktile 2i : phases 1-4 ----------------
        // ph1: read A(mh0) 8 + B(nh0) 4; stage buf1.Ah1<-kt1
#pragma unroll
        for (int m = 0; m < 4; ++m) {
            const int o = aob + m * 2048;
            af[m][0] = *(const bf16x8*)(sb0 + o);
            af[m][1] = *(const bf16x8*)(sb0 + (o ^ 64));
        }
#pragma unroll
        for (int n = 0; n < 2; ++n) {
            const int o = bob + n * 2048;
            bfr[n][0] = *(const bf16x8*)(sb0 + o);
            bfr[n][1] = *(const bf16x8*)(sb0 + (o ^ 64));
        }
        SH(65536 + 16384, gA1, kt1);
        __builtin_amdgcn_s_barrier();
        asm volatile("s_waitcnt lgkmcnt(0)" ::: "memory");
        __builtin_amdgcn_s_setprio(1);
#pragma unroll
        for (int m = 0; m < 4; ++m)
#pragma unroll
            for (int n = 0; n < 2; ++n) {
                acc[m][n] = MFMA16(af[m][0], bfr[n][0], acc[m][n], 0, 0, 0);
                acc[m][n] = MFMA16(af[m][1], bfr[n][1], acc[m][n], 0, 0, 0);
            }
        __builtin_amdgcn_s_setprio(0);
        __builtin_amdgcn_s_barrier();

        // ph2: read B(nh1) 4; stage buf1.Bh0<-kt1
#pragma unroll
        for (int n = 2; n < 4; ++n) {
            const int o = bob + n * 2048;
            bfr[n][0] = *(const bf16x8*)(sb0 + o);
            bfr[n][1] = *(const bf16x8*)(sb0 + (o ^ 64));
        }
        SH(65536 + 32768, gB0, kt1);
        __builtin_amdgcn_s_barrier();
        asm volatile("s_waitcnt lgkmcnt(0)" ::: "memory");
        __builtin_amdgcn_s_setprio(1);
#pragma unroll
        for (int m = 0; m < 4; ++m)
#pragma unroll
            for (int n = 2; n < 4; ++n) {
                acc[m][n] = MFMA16(af[m][0], bfr[n][0], acc[m][n], 0, 0, 0);
                acc[m][n] = MFMA16(af[m][1], bfr[n][1], acc[m][n], 0, 0, 0);
            }
        __builtin_amdgcn_s_setprio(0);
        __builtin_amdgcn_s_barrier();

        // ph3: read A(mh1) 8; stage buf1.Bh1<-kt1
#pragma unroll
        for (int m = 0; m < 4; ++m) {
            const int o = aob + 8192 + m * 2048;
            af[m][0] = *(const bf16x8*)(sb0 + o);
            af[m][1] = *(const bf16x8*)(sb0 + (o ^ 64));
        }
        SH(65536 + 49152, gB1, kt1);
        __builtin_amdgcn_s_barrier();
        asm volatile("s_waitcnt lgkmcnt(0)" ::: "memory");
        __builtin_amdgcn_s_setprio(1);
#pragma unroll
        for (int m = 0; m < 4; ++m)
#pragma unroll
            for (int n = 0; n < 2; ++n) {
                acc[m + 4][n] = MFMA16(af[m][0], bfr[n][0], acc[m + 4][n], 0, 0, 0);
                acc[m + 4][n] = MFMA16(af[m][1], bfr[n][1], acc[m + 4][n], 0, 0, 0);
            }
        __builtin_amdgcn_s_setprio(0);
        __builtin_amdgcn_s_barrier();

        // ph4: no reads; stage buf0.Ah0<-kt2; vmcnt (buf1 ready)
        if (more) { SH(0, gA0, kt2); asm volatile("s_waitcnt vmcnt(6)" ::: "memory"); }
        else      {                  asm volatile("s_waitcnt vmcnt(0)" ::: "memory"); }
        __builtin_amdgcn_s_barrier();
        __builtin_amdgcn_s_setprio(1);
#pragma unroll
        for (int m = 0; m < 4; ++m)
#pragma unroll
            for (int n = 2; n < 4; ++n) {
                acc[m + 4][n] = MFMA16(af[m][0], bfr[n][0], acc[m + 4][n], 0, 0, 0);
                acc[m + 4][n] = MFMA16(af[m][1], bfr[n][1], acc[m + 4][n], 0, 0, 0);
            }
        __builtin_amdgcn_s_setprio(0);
        __builtin_amdgcn_s_barrier();

        // ---------------- buf1 = ktile 2i+1 : phases 5-8 ----------------
        // ph5: read A(mh0) 8 + B(nh0) 4; stage buf0.Ah1<-kt2
#pragma unroll
        for (int m = 0; m < 4; ++m) {
            const int o = aob + m * 2048;
            af[m][0] = *(const bf16x8*)(sb1 + o);
            af[m][1] = *(const bf16x8*)(sb1 + (o ^ 64));
        }
#pragma unroll
        for (int n = 0; n < 2; ++n) {
            const int o = bob + n * 2048;
            bfr[n][0] = *(const bf16x8*)(sb1 + o);
            bfr[n][1] = *(const bf16x8*)(sb1 + (o ^ 64));
        }
        if (more) SH(16384, gA1, kt2);
        __builtin_amdgcn_s_barrier();
        asm volatile("s_waitcnt lgkmcnt(0)" ::: "memory");
        __builtin_amdgcn_s_setprio(1);
#pragma unroll
        for (int m = 0; m < 4; ++m)
#pragma unroll
            for (int n = 0; n < 2; ++n) {
                acc[m][n] = MFMA16(af[m][0], bfr[n][0], acc[m][n], 0, 0, 0);
                acc[m][n] = MFMA16(af[m][1], bfr[n][1], acc[m][n], 0, 0, 0);
            }
        __builtin_amdgcn_s_setprio(0);
        __builtin_amdgcn_s_barrier();

        // ph6: read B(nh1) 4; stage buf0.Bh0<-kt2
#pragma unroll
        for (int n = 2; n < 4; ++n) {
            const int o = bob + n * 2048;
            bfr[n][0] = *(const bf16x8*)(sb1 + o);
            bfr[n][1] = *(const bf16x8*)(sb1 + (o ^ 64));
        }
        if (more) SH(32768, gB0, kt2);
        __builtin_amdgcn_s_barrier();
        asm volatile("s_waitcnt lgkmcnt(0)" ::: "memory");
        __builtin_amdgcn_s_setprio(1);
#pragma unroll
        for (int m = 0; m < 4; ++m)
#pragma unroll
            for (int n = 2; n < 4; ++n) {
                acc[m][n] = MFMA16(af[m][0], bfr[n][0], acc[m][n], 0, 0, 0);
                acc[m][n] = MFMA16(af[m][1], bfr[n][1], acc[m][n], 0, 0, 0);
            }
        __builtin_amdgcn_s_setprio(0);
        __builtin_amdgcn_s_barrier();

        // ph7: read A(mh1) 8; stage buf0.Bh1<-kt2
#pragma unroll
        for (int m = 0; m < 4; ++m) {
            const int o = aob + 8192 + m * 2048;
            af[m][0] = *(const bf16x8*)(sb1 + o);
            af[m][1] = *(const bf16x8*)(sb1 + (o ^ 64));
        }
        if (more) SH(49152, gB1, kt2);
        __builtin_amdgcn_s_barrier();
        asm volatile("s_waitcnt lgkmcnt(0)" ::: "memory");
        __builtin_amdgcn_s_setprio(1);
#pragma unroll
        for (int m = 0; m < 4; ++m)
#pragma unroll
            for (int n = 0; n < 2; ++n) {
                acc[m + 4][n] = MFMA16(af[m][0], bfr[n][0], acc[m + 4][n], 0, 0, 0);
                acc[m + 4][n] = MFMA16(af[m][1], bfr[n][1], acc[m + 4][n], 0, 0, 0);
            }
        __builtin_amdgcn_s_setprio(0);
        __builtin_amdgcn_s_barrier();

        // ph8: no reads; stage buf1.Ah0<-kt3; vmcnt (next buf0 ready)
        if (more) { SH(65536, gA0, kt3); asm volatile("s_waitcnt vmcnt(6)" ::: "memory"); }
        __builtin_amdgcn_s_barrier();
        __builtin_amdgcn_s_setprio(1);
#pragma unroll
        for (int m = 0; m < 4; ++m)
#pragma unroll
            for (int n = 2; n < 4; ++n) {
                acc[m + 4][n] = MFMA16(af[m][0], bfr[n][0], acc[m + 4][n], 0, 0, 0);
                acc[m + 4][n] = MFMA16(af[m][1], bfr[n][1], acc[m + 4][n], 0, 0, 0);
            }
        __builtin_amdgcn_s_setprio(0);
        __builtin_amdgcn_s_barrier();
    }
#undef SH

    // epilogue: coalesced bf16 stores via LDS, two 128-row halves (stride 260)
    u16* cs = (u16*)smem8;
#pragma unroll
    for (int hh = 0; hh < 2; ++hh) {
        __builtin_amdgcn_s_barrier();
        if (wr == hh) {
#pragma unroll
            for (int ni = 0; ni < 4; ++ni) {
                const int col = wc * 64 + ni * 16 + fr;
                const float bv = bias[n0 + col];
#pragma unroll
                for (int mi = 0; mi < 8; ++mi) {
#pragma unroll
                    for (int j = 0; j < 4; ++j) {
                        float val = acc[mi][ni][j] + bv;
                        if (EPI == 1)
                            val = 0.5f * val * (1.0f + erff(val * 0.70710678118654752f));
                        cs[(mi * 16 + fq * 4 + j) * 260 + col] = f2bf(val);
                    }
                }
            }
        }
        __builtin_amdgcn_s_barrier();
        const int cc = (tid & 31) * 8;
#pragma unroll
        for (int p = 0; p < 8; ++p) {
            const int row = p * 16 + (tid >> 5);
            const uint64_t lo = *(const uint64_t*)&cs[row * 260 + cc];
            const uint64_t hi = *(const uint64_t*)&cs[row * 260 + cc + 4];
            u64x2 v; v.x = lo; v.y = hi;
            *(u64x2*)&Cb[(size_t)(m0 + hh * 128 + row) * N + n0 + cc] = v;
        }
    }
}

// ---------------------------------------------------------------------------
// GEMM (128x128, 2-phase pipeline): C = A * Wt^T (+bias) (+epilogue)
//   EPI 2: +bias, += resid (fp32), store fp32
//   EPI 3: split-K partial, no bias, fp32 to (blockIdx.y ? Cf2 : Cf)
// ---------------------------------------------------------------------------
template <int EPI>
__global__ __launch_bounds__(256) void gemm_bt(
    const u16* __restrict__ A, const u16* __restrict__ A2,
    const u16* __restrict__ Wt,
    const float* __restrict__ bias, const float* __restrict__ resid,
    u16* __restrict__ Cb, float* __restrict__ Cf, float* __restrict__ Cf2,
    int N, int K, int kl, int gx, int cx)
{
    extern __shared__ __align__(16) char smem[];   // 2x16KB stage

    const int bid = blockIdx.x;
    const int xcd = bid & 7, jj = bid >> 3;
    const int sx = gx / cx;
    const int sy = (gridDim.x >> 3) / sx;
    const int xr = xcd / cx, xc = xcd % cx;
    const int jr = jj / sx, jc = jj % sx;
    const int m0 = (xr * sy + jr) * 128;
    const int n0 = (xc * sx + jc) * 128;
    const int kofs = blockIdx.y * kl;

    const int t = threadIdx.x;
    const int lane = t & 63;
    const int wv = t >> 6;
    const int wr = wv >> 1, wc = wv & 1;

    const u16* Ause = (A2 != nullptr && n0 >= 1024) ? A2 : A;

    const int strow = t >> 2;            // 0..63
    const int stcol = (t & 3) * 8;
    const u16* gA  = Ause + (size_t)(m0 + strow) * K + kofs + stcol;
    const u16* gA2 = gA + (size_t)64 * K;
    const u16* gB  = Wt + (size_t)(n0 + strow) * K + kofs + stcol;
    const u16* gB2 = gB + (size_t)64 * K;

#define STAGE(bufi, k0) do {                                                            \
    char* _b = smem + (bufi) * 16384 + wv * 1024;                                       \
    __builtin_amdgcn_global_load_lds((const glb_u32_t*)(gA  + (k0)), (lds_u32_t*)(_b),          16, 0, 0); \
    __builtin_amdgcn_global_load_lds((const glb_u32_t*)(gA2 + (k0)), (lds_u32_t*)(_b + 4096),  16, 0, 0); \
    __builtin_amdgcn_global_load_lds((const glb_u32_t*)(gB  + (k0)), (lds_u32_t*)(_b + 8192),  16, 0, 0); \
    __builtin_amdgcn_global_load_lds((const glb_u32_t*)(gB2 + (k0)), (lds_u32_t*)(_b + 12288), 16, 0, 0); \
} while (0)

    f32x4 zero = {0.f, 0.f, 0.f, 0.f};
    f32x4 acc[4][4];
#pragma unroll
    for (int mi = 0; mi < 4; ++mi)
#pragma unroll
        for (int ni = 0; ni < 4; ++ni) acc[mi][ni] = zero;

    const int fr = lane & 15, fq = lane >> 4;
    const int nk = kl >> 5;

    STAGE(0, 0);
    STAGE(1, 32);

    for (int kt = 0; kt < nk; ++kt) {
        const int cur = kt & 1;
        if (kt < nk - 1) { asm volatile("s_waitcnt vmcnt(4)" ::: "memory"); }
        else             { asm volatile("s_waitcnt vmcnt(0)" ::: "memory"); }
        __builtin_amdgcn_s_barrier();

        const u16* As_ = (const u16*)smem + cur * 8192;
        const u16* Bs_ = As_ + 4096;
        bf16x8 af[4], bfr[4];
#pragma unroll
        for (int mi = 0; mi < 4; ++mi)
            af[mi] = *(const bf16x8*)&As_[(wr * 64 + mi * 16 + fr) * 32 + fq * 8];
#pragma unroll
        for (int ni = 0; ni < 4; ++ni)
            bfr[ni] = *(const bf16x8*)&Bs_[(wc * 64 + ni * 16 + fr) * 32 + fq * 8];

        __builtin_amdgcn_s_setprio(1);
#pragma unroll
        for (int mi = 0; mi < 4; ++mi)
#pragma unroll
            for (int ni = 0; ni < 4; ++ni)
                acc[mi][ni] = MFMA16(af[mi], bfr[ni], acc[mi][ni], 0, 0, 0);
        __builtin_amdgcn_s_setprio(0);
        __builtin_amdgcn_sched_barrier(0);
        __builtin_amdgcn_s_barrier();
        if (kt + 2 < nk) STAGE(cur, (kt + 2) << 5);
    }
#undef STAGE

    float* Cpart = (EPI == 3) ? (blockIdx.y ? Cf2 : Cf) : Cf;
#pragma unroll
    for (int ni = 0; ni < 4; ++ni) {
        const int col = n0 + wc * 64 + ni * 16 + fr;
        const float bv = (EPI == 3) ? 0.f : bias[col];
#pragma unroll
        for (int mi = 0; mi < 4; ++mi) {
#pragma unroll
            for (int j = 0; j < 4; ++j) {
                const int row = m0 + wr * 64 + mi * 16 + fq * 4 + j;
                float val = acc[mi][ni][j] + bv;
                if (EPI == 2)
                    Cf[(size_t)row * N + col] = val + resid[(size_t)row * N + col];
                else
                    Cpart[(size_t)row * N + col] = val;
            }
        }
    }
}

// ---------------------------------------------------------------------------
// Split-K reduce: out = p0 + p1 + bias + resid  (fp32, vectorized)
// ---------------------------------------------------------------------------
__global__ __launch_bounds__(256) void redk_kernel(
    const float* __restrict__ p0, const float* __restrict__ p1,
    const float* __restrict__ bias, const float* __restrict__ resid,
    float* __restrict__ out, int n4, int ncols)
{
    const int stride = gridDim.x * 256;
    for (int i = blockIdx.x * 256 + threadIdx.x; i < n4; i += stride) {
        const float4 a = ((const float4*)p0)[i];
        const float4 b = ((const float4*)p1)[i];
        const float4 r = ((const float4*)resid)[i];
        const float4 bb = *(const float4*)&bias[(i * 4) & (ncols - 1)];
        float4 o;
        o.x = a.x + b.x + bb.x + r.x;
        o.y = a.y + b.y + bb.y + r.y;
        o.z = a.z + b.z + bb.z + r.z;
        o.w = a.w + b.w + bb.w + r.w;
        ((float4*)out)[i] = o;
    }
}

// ---------------------------------------------------------------------------
// Banded attention via MFMA. One wave = 16 queries x 80-key aligned window
// (supports band <= 32). q,k read from fused qkv [4096][3072]; ctx -> [4096][1024].
// ---------------------------------------------------------------------------
__global__ __launch_bounds__(256) void battn_kernel(
    const u16* __restrict__ qkv, const u16* __restrict__ vT,
    u16* __restrict__ ctx, const int* __restrict__ band_ptr)
{
    __shared__ __align__(16) u16 P[4][16][104];
    const int band = *band_ptr;
    const int bid = blockIdx.x;
    const int tile = bid & 31;
    const int h = (bid >> 5) & 15;
    const int b = bid >> 9;
    const int w = threadIdx.x >> 6;
    const int lane = threadIdx.x & 63;
    const int fr = lane & 15, fq = lane >> 4;
    const int t0 = tile * 64 + w * 16;

    const size_t qbase = ((size_t)b * TSEQ) * 3072 + h * DHEAD;          // q cols
    const size_t kbase = qbase + 1024;                                   // k cols
    const size_t cbase = ((size_t)b * TSEQ) * DMODEL + h * DHEAD;        // ctx

    const bf16x8 aq0 = *(const bf16x8*)&qkv[qbase + (size_t)(t0 + fr) * 3072 + fq * 8];
    const bf16x8 aq1 = *(const bf16x8*)&qkv[qbase + (size_t)(t0 + fr) * 3072 + 32 + fq * 8];

    const int kb0 = t0 - 32;
    const f32x4 zero = {0.f, 0.f, 0.f, 0.f};

    f32x4 sc[5];
#pragma unroll
    for (int kt = 0; kt < 5; ++kt) {
        const int srow = kb0 + kt * 16 + fr;
        const int scl = min(max(srow, 0), TSEQ - 1);
        const bf16x8 kf0 = *(const bf16x8*)&qkv[kbase + (size_t)scl * 3072 + fq * 8];
        const bf16x8 kf1 = *(const bf16x8*)&qkv[kbase + (size_t)scl * 3072 + 32 + fq * 8];
        f32x4 a = zero;
        a = MFMA16(aq0, kf0, a, 0, 0, 0);
        a = MFMA16(aq1, kf1, a, 0, 0, 0);
        sc[kt] = a;
    }

    float mx[4], l[4];
#pragma unroll
    for (int j = 0; j < 4; ++j) mx[j] = -1e30f;
#pragma unroll
    for (int kt = 0; kt < 5; ++kt) {
        const int s = kb0 + kt * 16 + fr;
#pragma unroll
        for (int j = 0; j < 4; ++j) {
            const int tq = t0 + fq * 4 + j;
            const bool ok = (s >= 0) && (s < TSEQ) && (abs(tq - s) <= band);
            const float vv = ok ? sc[kt][j] * 0.125f : -1e30f;
            sc[kt][j] = vv;
            mx[j] = fmaxf(mx[j], vv);
        }
    }
#pragma unroll
    for (int m = 1; m <= 8; m <<= 1)
#pragma unroll
        for (int j = 0; j < 4; ++j) mx[j] = fmaxf(mx[j], __shfl_xor(mx[j], m));

#pragma unroll
    for (int j = 0; j < 4; ++j) l[j] = 0.f;
#pragma unroll
    for (int kt = 0; kt < 5; ++kt)
#pragma unroll
        for (int j = 0; j < 4; ++j) {
            const float p = __expf(sc[kt][j] - mx[j]);
            sc[kt][j] = p;
            l[j] += p;
        }
#pragma unroll
    for (int m = 1; m <= 8; m <<= 1)
#pragma unroll
        for (int j = 0; j < 4; ++j) l[j] += __shfl_xor(l[j], m);

#pragma unroll
    for (int kt = 0; kt < 5; ++kt)
#pragma unroll
        for (int j = 0; j < 4; ++j)
            P[w][fq * 4 + j][kt * 16 + fr] = f2bf(sc[kt][j]);
    {
        const short4 z4 = {0, 0, 0, 0};
        *(short4*)&P[w][fr][80 + fq * 4] = z4;
    }
    __syncthreads();

    bf16x8 pa[3];
#pragma unroll
    for (int c = 0; c < 3; ++c)
        pa[c] = *(const bf16x8*)&P[w][fr][c * 32 + fq * 8];

    const size_t vbase = ((size_t)(b * NHEAD + h) * DHEAD) * TSEQ;
    f32x4 cacc[4];
#pragma unroll
    for (int dt = 0; dt < 4; ++dt) cacc[dt] = zero;
#pragma unroll
    for (int dt = 0; dt < 4; ++dt) {
#pragma unroll
        for (int c = 0; c < 3; ++c) {
            const int s8 = kb0 + c * 32 + fq * 8;
            const int s8c = min(max(s8, 0), TSEQ - 8);
            const bf16x8 vf = *(const bf16x8*)&vT[vbase + (size_t)(dt * 16 + fr) * TSEQ + s8c];
            cacc[dt] = MFMA16(pa[c], vf, cacc[dt], 0, 0, 0);
        }
    }

    float rl[4];
#pragma unroll
    for (int j = 0; j < 4; ++j) rl[j] = 1.0f / l[j];
#pragma unroll
    for (int dt = 0; dt < 4; ++dt)
#pragma unroll
        for (int j = 0; j < 4; ++j)
            ctx[cbase + (size_t)(t0 + fq * 4 + j) * DMODEL + dt * 16 + fr] =
                f2bf(cacc[dt][j] * rl[j]);
}

// ---------------------------------------------------------------------------
extern "C" void kernel_launch(void* const* d_in, const int* in_sizes, int n_in,
                              void* d_out, int out_size, void* d_ws, size_t ws_size,
                              hipStream_t stream) {
    const float* x_ref  = (const float*)d_in[0];
    const float* x_mem  = (const float*)d_in[1];
    const float* ln_q_g = (const float*)d_in[2];
    const float* ln_q_b = (const float*)d_in[3];
    const float* ln_kv_g= (const float*)d_in[4];
    const float* ln_kv_b= (const float*)d_in[5];
    const float* Wq = (const float*)d_in[6];
    const float* bq = (const float*)d_in[7];
    const float* Wk = (const float*)d_in[8];
    const float* bk = (const float*)d_in[9];
    const float* Wv = (const float*)d_in[10];
    const float* bv = (const float*)d_in[11];
    const float* Wo = (const float*)d_in[12];
    const float* bo = (const float*)d_in[13];
    const float* ln_f_g = (const float*)d_in[14];
    const float* ln_f_b = (const float*)d_in[15];
    const float* W1 = (const float*)d_in[16];
    const float* b1 = (const float*)d_in[17];
    const float* W2 = (const float*)d_in[18];
    const float* b2 = (const float*)d_in[19];
    const int*  band = (const int*)d_in[20];
    float* out = (float*)d_out;

    char* ws = (char*)d_ws;
    const size_t MB = 1024 * 1024;
    if (ws_size < 128 * MB) return;
    u16*   wt_qkv = (u16*)(ws + 0 * MB);
    u16*   wt_o   = (u16*)(ws + 6 * MB);
    u16*   wt_1   = (u16*)(ws + 8 * MB);
    u16*   wt_2   = (u16*)(ws + 16 * MB);
    float* bqkv   = (float*)(ws + 24 * MB);
    u16*   aq     = (u16*)(ws + 25 * MB);
    u16*   akv    = (u16*)(ws + 33 * MB);
    u16*   qkvb   = (u16*)(ws + 41 * MB);
    u16*   vTb    = (u16*)(ws + 65 * MB);
    u16*   ctxb   = (u16*)(ws + 73 * MB);
    float* y      = (float*)(ws + 81 * MB);
    u16*   hb     = (u16*)(ws + 97 * MB);
    u16*   a1     = (u16*)(ws + 25 * MB);
    float* p0     = (float*)(ws + 57 * MB);
    float* p1     = (float*)(ws + 97 * MB);

    dim3 blk(256);
    const size_t SM_GEMM = 32768;   // 2x16KB stage buffers

    tc_kernel<<<dim3(32, 32),  blk, 0, stream>>>(Wq, wt_qkv,               1024, 1024);
    tc_kernel<<<dim3(32, 32),  blk, 0, stream>>>(Wk, wt_qkv + 1024 * 1024, 1024, 1024);
    tc_kernel<<<dim3(32, 32),  blk, 0, stream>>>(Wv, wt_qkv + 2048 * 1024, 1024, 1024);
    tc_kernel<<<dim3(32, 32),  blk, 0, stream>>>(Wo, wt_o, 1024, 1024);
    tc_kernel<<<dim3(128, 32), blk, 0, stream>>>(W1, wt_1, 1024, 4096);
    tc_kernel<<<dim3(32, 128), blk, 0, stream>>>(W2, wt_2, 4096, 1024);
    biaspack_kernel<<<12, blk, 0, stream>>>(bq, bk, bv, bqkv);
    ln_kernel<<<MROWS, blk, 0, stream>>>(x_ref, ln_q_g, ln_q_b, aq);
    ln_kernel<<<MROWS, blk, 0, stream>>>(x_mem, ln_kv_g, ln_kv_b, akv);
    // fused QKV projection: [4096][3072]; 256^2 tiles 16y x 12x; XCD 4r x 2c
    gemm256<0><<<dim3(192), dim3(512), 0, stream>>>(aq, akv, wt_qkv, bqkv, qkvb,
                                                    3072, 1024, 12, 2);
    vt_kernel<<<dim3(32, 16, 2), blk, 0, stream>>>(qkvb, vTb);
    battn_kernel<<<1024, blk, 0, stream>>>(qkvb, vTb, ctxb, band);
    // y = x_refined + ctx @ Wo + bo; 128^2 tiles 32y x 8x
    gemm_bt<2><<<dim3(256), blk, SM_GEMM, stream>>>(ctxb, nullptr, wt_o, bo, x_ref,
                                                    nullptr, y, nullptr,
                                                    1024, 1024, 1024, 8, 1);
    ln_kernel<<<MROWS, blk, 0, stream>>>(y, ln_f_g, ln_f_b, hb);
    // FFN1: GELU(hb @ W1 + b1); 256^2 tiles 16y x 16x; XCD 4r x 2c
    gemm256<1><<<dim3(256), dim3(512), 0, stream>>>(hb, nullptr, wt_1, b1, a1,
                                                    4096, 1024, 16, 2);
    // FFN2 split-K=2; 128^2 tiles 32y x 8x
    gemm_bt<3><<<dim3(256, 2), blk, SM_GEMM, stream>>>(a1, nullptr, wt_2, nullptr, nullptr,
                                                       nullptr, p0, p1,
                                                       1024, 4096, 2048, 8, 1);
    redk_kernel<<<2048, blk, 0, stream>>>(p0, p1, b2, y, out, MROWS * 1024 / 4, 1024);
}